// Round 1
// baseline (1549.818 us; speedup 1.0000x reference)
//
#include <hip/hip_runtime.h>
#include <hip/hip_bf16.h>
#include <hip/hip_fp16.h>

// SVD-RNN: W = U diag(s) V from Householder chains; h_t = tanh(xp_t + W h_{t-1});
// out_t = h_t W_out^T + b_out.
#define BB 64
#define TT 2048
#define II 128
#define HH 256
#define OO 128
#define RCH 8                      // recurrence chunk length (global I/O batching)

typedef _Float16 f16x2 __attribute__((ext_vector_type(2)));
typedef _Float16 f16x8 __attribute__((ext_vector_type(8)));
typedef float f32x4 __attribute__((ext_vector_type(4)));

#if __has_builtin(__builtin_amdgcn_fdot2)
__device__ __forceinline__ float fdot2(f16x2 a, f16x2 b, float c) {
    return __builtin_amdgcn_fdot2(a, b, c, false);
}
#else
__device__ __forceinline__ float fdot2(f16x2 a, f16x2 b, float c) {
    return fmaf((float)a.x, (float)b.x, fmaf((float)a.y, (float)b.y, c));
}
#endif

__device__ __forceinline__ f16x2 u2h(unsigned int u) { return __builtin_bit_cast(f16x2, u); }
__device__ __forceinline__ unsigned int packf16(float a, float b) {
    return __builtin_bit_cast(unsigned int, f16x2{(_Float16)a, (_Float16)b});
}

__device__ __forceinline__ float tanh_fast(float x) {
    float xc = fminf(fmaxf(x, -9.0f), 9.0f);
    float e = __expf(2.0f * xc);
    return (e - 1.0f) * __fdividef(1.0f, e + 1.0f);
}

// lgkm-only workgroup barrier: orders LDS writes/reads across waves WITHOUT
// draining vmcnt, so chunked global prefetch/stores stay in flight across
// steps (stock __syncthreads emits s_waitcnt vmcnt(0) expcnt(0) lgkmcnt(0)
// and would expose the xp prefetch HBM latency once per chunk).
__device__ __forceinline__ void step_barrier() {
    __builtin_amdgcn_sched_barrier(0);
    asm volatile("s_waitcnt lgkmcnt(0)" ::: "memory");
    __builtin_amdgcn_s_barrier();
    __builtin_amdgcn_sched_barrier(0);
}

// ---------------------------------------------------------------------------
// Kernel 1: masked+flipped Householder vectors and betas.
// ---------------------------------------------------------------------------
__global__ __launch_bounds__(64) void prep_kernel(
    const float* __restrict__ u_raw, const float* __restrict__ v_raw,
    float* __restrict__ u_eff, float* __restrict__ v_eff,
    float* __restrict__ beta_u, float* __restrict__ beta_v)
{
    const int row = blockIdx.x;
    const int lane = threadIdx.x;
    const bool isU = row < HH;
    const int i = isU ? row : row - HH;
    const float* src = isU ? (u_raw + (size_t)i * HH) : (v_raw + (size_t)(HH - 1 - i) * HH);
    float* dst = (isU ? u_eff : v_eff) + (size_t)i * HH;
    const int lo = isU ? (HH - 1 - i) : i;
    float ss = 0.0f;
    for (int c = lane; c < HH; c += 64) {
        float vv = (c >= lo) ? src[HH - 1 - c] : 0.0f;
        dst[c] = vv;
        ss += vv * vv;
    }
    for (int m = 1; m < 64; m <<= 1) ss += __shfl_xor(ss, m, 64);
    if (lane == 0) (isU ? beta_u : beta_v)[i] = 2.0f / ss;
}

// ---------------------------------------------------------------------------
// Kernel 2: Householder chain per column.
// ---------------------------------------------------------------------------
__global__ __launch_bounds__(256) void hh_kernel(
    const float* __restrict__ u_eff, const float* __restrict__ v_eff,
    const float* __restrict__ beta_u, const float* __restrict__ beta_v,
    float* __restrict__ Ucol, float* __restrict__ Vrow)
{
    const int wid = blockIdx.x * 4 + (threadIdx.x >> 6);
    const int lane = threadIdx.x & 63;
    const bool isU = wid < HH;
    const int j = isU ? wid : wid - HH;
    const float* eff = isU ? u_eff : v_eff;
    const float* beta = isU ? beta_u : beta_v;

    float cr0 = (j == 4 * lane + 0) ? 1.0f : 0.0f;
    float cr1 = (j == 4 * lane + 1) ? 1.0f : 0.0f;
    float cr2 = (j == 4 * lane + 2) ? 1.0f : 0.0f;
    float cr3 = (j == 4 * lane + 3) ? 1.0f : 0.0f;

    const int i0 = isU ? (HH - 1 - j) : 0;
    for (int i = i0; i < HH; ++i) {
        const float4 v4 = *(const float4*)(eff + (size_t)i * HH + lane * 4);
        float d = v4.x * cr0 + v4.y * cr1 + v4.z * cr2 + v4.w * cr3;
        for (int m = 1; m < 64; m <<= 1) d += __shfl_xor(d, m, 64);
        const float t = beta[i] * d;
        cr0 = fmaf(-t, v4.x, cr0);
        cr1 = fmaf(-t, v4.y, cr1);
        cr2 = fmaf(-t, v4.z, cr2);
        cr3 = fmaf(-t, v4.w, cr3);
    }
    if (isU) {
        *(float4*)(Ucol + (size_t)j * HH + lane * 4) = make_float4(cr0, cr1, cr2, cr3);
    } else {
        Vrow[(size_t)(4 * lane + 0) * HH + j] = cr0;
        Vrow[(size_t)(4 * lane + 1) * HH + j] = cr1;
        Vrow[(size_t)(4 * lane + 2) * HH + j] = cr2;
        Vrow[(size_t)(4 * lane + 3) * HH + j] = cr3;
    }
}

// ---------------------------------------------------------------------------
// Kernel 3: W[r][c] = sum_k Ucol[k][r] * sig[k] * Vrow[k][c]
// ---------------------------------------------------------------------------
__global__ __launch_bounds__(256) void w_kernel(
    const float* __restrict__ Ucol, const float* __restrict__ Vrow,
    const float* __restrict__ sig, float* __restrict__ Wm)
{
    const int r = blockIdx.x;
    const int c = threadIdx.x;
    float acc = 0.0f;
    #pragma unroll 4
    for (int k = 0; k < HH; ++k) {
        acc = fmaf(Ucol[(size_t)k * HH + r] * sig[k], Vrow[(size_t)k * HH + c], acc);
    }
    Wm[(size_t)r * HH + c] = acc;
}

// ---------------------------------------------------------------------------
// MFMA tiled GEMM with bias: C[M][N] = A[M][K] * B[N][K]^T + bias[N].
// BM=128, BN=64, BK=32; 256 threads = 4 waves, each wave a 64x32 quadrant
// (4 m-tiles x 2 n-tiles of 16x16, mfma_f32_16x16x32_f16).
// ---------------------------------------------------------------------------
__device__ __forceinline__ void stage16(_Float16* dst, const float* src) {
    #pragma unroll
    for (int i = 0; i < 4; ++i) {
        float4 f = ((const float4*)src)[i];
        ((f16x2*)dst)[2 * i + 0] = f16x2{(_Float16)f.x, (_Float16)f.y};
        ((f16x2*)dst)[2 * i + 1] = f16x2{(_Float16)f.z, (_Float16)f.w};
    }
}
__device__ __forceinline__ void stage16(_Float16* dst, const __half* src) {
    ((uint4*)dst)[0] = ((const uint4*)src)[0];
    ((uint4*)dst)[1] = ((const uint4*)src)[1];
}
__device__ __forceinline__ void storeC(float* p, float v) { *p = v; }
__device__ __forceinline__ void storeC(__half* p, float v) { *p = __float2half_rn(v); }

template <typename AT, typename OT>
__global__ __launch_bounds__(256) void gemm_mfma(
    const AT* __restrict__ A, const float* __restrict__ Bm,
    const float* __restrict__ bias, OT* __restrict__ C,
    int M, int N, int K)
{
    __shared__ _Float16 As[128][40];
    __shared__ _Float16 Bs[64][40];
    const int tid = threadIdx.x;
    const int m0 = blockIdx.x * 128;
    const int n0 = blockIdx.y * 64;
    const int lane = tid & 63;
    const int w = tid >> 6;
    const int lo = lane & 15;
    const int qd = lane >> 4;
    const int mh = w >> 1;               // m-half (64 rows)
    const int nh = w & 1;                // n-half (32 cols)
    const int srow = tid >> 1;           // staging row 0..127
    const int shalf = tid & 1;           // 16-f16 half of the 32-k row

    f32x4 acc[4][2] = {};
    for (int k0 = 0; k0 < K; k0 += 32) {
        stage16(&As[srow][shalf * 16], A + (size_t)(m0 + srow) * K + k0 + shalf * 16);
        if (tid < 128)
            stage16(&Bs[srow][shalf * 16], Bm + (size_t)(n0 + srow) * K + k0 + shalf * 16);
        __syncthreads();
        f16x8 af[4], bf[2];
        #pragma unroll
        for (int mt = 0; mt < 4; ++mt)
            af[mt] = *(const f16x8*)&As[64 * mh + 16 * mt + lo][qd * 8];
        #pragma unroll
        for (int nt = 0; nt < 2; ++nt)
            bf[nt] = *(const f16x8*)&Bs[32 * nh + 16 * nt + lo][qd * 8];
        #pragma unroll
        for (int mt = 0; mt < 4; ++mt)
            #pragma unroll
            for (int nt = 0; nt < 2; ++nt)
                acc[mt][nt] = __builtin_amdgcn_mfma_f32_16x16x32_f16(
                    af[mt], bf[nt], acc[mt][nt], 0, 0, 0);
        __syncthreads();
    }
    #pragma unroll
    for (int nt = 0; nt < 2; ++nt) {
        const int n = n0 + 32 * nh + 16 * nt + lo;
        const float bv = bias[n];
        #pragma unroll
        for (int mt = 0; mt < 4; ++mt) {
            const int m = m0 + 64 * mh + 16 * mt + 4 * qd;
            #pragma unroll
            for (int r = 0; r < 4; ++r)
                storeC(C + (size_t)(m + r) * N + n, acc[mt][nt][r] + bv);
        }
    }
}

// ---------------------------------------------------------------------------
// Kernel 5: recurrence — ROW-SPLIT, single lgkm-barrier per step.
// 64 WGs x 512 threads (8 waves). Wave q owns output rows [32q, 32q+32);
// lane pair (l, l+32) owns one full row (row = 32q + (l&63 & 31)), each lane
// half of K=256 (64 f16x2 of W in VGPRs). Per step:
//   dot (16 uniform b128 LDS reads of packed h + 64 dot2, 4 acc chains)
//   -> cross-half combine via __shfl_xor(32) -> tanh -> pair-pack via
//   __shfl_xor(1) -> even lanes<32 write 16 uints to 1KB double-buffered
//   hbuf -> lgkm-only barrier.  ONE barrier/step (vs 2 before), all
//   reduce/tanh pre-barrier and in-register (no ps[] LDS reduction), and
//   vmcnt never drains in-loop so chunked xp prefetch / hall stores are
//   fully hidden.  Single-barrier safety: all reads of hbuf[p] drain at
//   step-s barrier (lgkmcnt(0)) before any wave reaches step s+1 which
//   overwrites hbuf[p].
// ---------------------------------------------------------------------------
__global__ __launch_bounds__(512) void recur_kernel(
    const float* __restrict__ Wm,              // [256][256] f32 row-major
    const __half* __restrict__ xp,             // [B][T][256] f16
    __half* __restrict__ hall)                 // [B][T][256] f16
{
    const int b = blockIdx.x;
    const int tid = threadIdx.x;
    const int l = tid & 63;
    const int q = tid >> 6;        // wave 0..7
    const int lr = l & 31;         // row offset within wave's 32-row slice
    const int kh = l >> 5;         // k-half 0/1

    __shared__ __align__(16) unsigned int hbuf[2][HH / 2];  // packed f16x2 h, dbuf (1 KB)

    // W fragment: full row (32q+lr), k-range [128*kh, 128*kh+128), 64 f16x2.
    const int row = 32 * q + lr;
    f16x2 w2[64];
    {
        const float* Wp = Wm + (size_t)row * HH + 128 * kh;
        #pragma unroll
        for (int c4 = 0; c4 < 32; ++c4) {
            float4 f = *(const float4*)(Wp + 4 * c4);
            w2[2 * c4 + 0] = f16x2{(_Float16)f.x, (_Float16)f.y};
            w2[2 * c4 + 1] = f16x2{(_Float16)f.z, (_Float16)f.w};
        }
    }
    if (tid < HH) ((unsigned int*)hbuf)[tid] = 0u;   // zero both buffers
    __syncthreads();

    const _Float16* xph = (const _Float16*)xp + (size_t)b * TT * HH + row;
    unsigned int* hw = (unsigned int*)(hall + (size_t)b * TT * HH) + 16 * q + (lr >> 1);
    const bool wr = (l < 32) && ((l & 1) == 0);      // even lanes of first half

    _Float16 xpc[RCH], xpn[RCH];
    unsigned int hst[RCH];
    #pragma unroll
    for (int s = 0; s < RCH; ++s) xpc[s] = xph[(size_t)s * HH];

    int p = 0;
    const int nch = TT / RCH;
    for (int c = 0; c < nch; ++c) {
        if (c + 1 < nch) {
            const _Float16* xn = xph + (size_t)(c + 1) * RCH * HH;
            #pragma unroll
            for (int s = 0; s < RCH; ++s) xpn[s] = xn[(size_t)s * HH];
        }
        #pragma unroll
        for (int s = 0; s < RCH; ++s) {
            // dot: h broadcast from LDS (uniform per half-wave, 16B granules)
            const uint4* hb = (const uint4*)(&hbuf[p][0]) + kh * 16;
            float a0 = 0.f, a1 = 0.f, a2 = 0.f, a3 = 0.f;
            #pragma unroll
            for (int g = 0; g < 16; ++g) {
                uint4 h4 = hb[g];
                a0 = fdot2(w2[4 * g + 0], u2h(h4.x), a0);
                a1 = fdot2(w2[4 * g + 1], u2h(h4.y), a1);
                a2 = fdot2(w2[4 * g + 2], u2h(h4.z), a2);
                a3 = fdot2(w2[4 * g + 3], u2h(h4.w), a3);
            }
            float part = (a0 + a1) + (a2 + a3);
            float tot = part + __shfl_xor(part, 32, 64);           // combine k-halves
            float hval = tanh_fast(tot + (float)xpc[s]);
            float hot = __shfl_xor(hval, 1, 64);                   // pair partner
            unsigned int pk = packf16(hval, hot);                  // valid in even lanes
            hst[s] = pk;
            if (wr) hbuf[p ^ 1][16 * q + (lr >> 1)] = pk;
            step_barrier();
            p ^= 1;
        }
        if (wr) {
            unsigned int* hwc = hw + (size_t)c * RCH * 128;
            #pragma unroll
            for (int s = 0; s < RCH; ++s) hwc[(size_t)s * 128] = hst[s];
        }
        #pragma unroll
        for (int s = 0; s < RCH; ++s) xpc[s] = xpn[s];
    }
}

// ---------------------------------------------------------------------------
extern "C" void kernel_launch(void* const* d_in, const int* in_sizes, int n_in,
                              void* d_out, int out_size, void* d_ws, size_t ws_size,
                              hipStream_t stream) {
    const float* x     = (const float*)d_in[0];   // [B][T][I]
    const float* W_in  = (const float*)d_in[1];   // [H][I]
    const float* b_in  = (const float*)d_in[2];   // [H]
    const float* W_out = (const float*)d_in[3];   // [O][H]
    const float* b_out = (const float*)d_in[4];   // [O]
    const float* u_raw = (const float*)d_in[5];   // [M][H]
    const float* sig   = (const float*)d_in[6];   // [H]
    const float* v_raw = (const float*)d_in[7];   // [M][H]
    float* out = (float*)d_out;                   // [B][T][O]

    char* ws = (char*)d_ws;
    size_t off = 0;
    auto alloc = [&](size_t bytes) -> void* {
        void* p = (void*)(ws + off);
        off += (bytes + 255) & ~((size_t)255);
        return p;
    };
    float* u_eff  = (float*)alloc((size_t)HH * HH * 4);
    float* v_eff  = (float*)alloc((size_t)HH * HH * 4);
    float* beta_u = (float*)alloc((size_t)HH * 4);
    float* beta_v = (float*)alloc((size_t)HH * 4);
    float* Ucol   = (float*)alloc((size_t)HH * HH * 4);
    float* Vrow   = (float*)alloc((size_t)HH * HH * 4);
    float* Wm     = (float*)alloc((size_t)HH * HH * 4);
    __half* xpbuf = (__half*)alloc((size_t)BB * TT * HH * 2);
    __half* hall  = (__half*)alloc((size_t)BB * TT * HH * 2);
    (void)ws_size; (void)in_sizes; (void)n_in; (void)out_size;

    prep_kernel<<<2 * HH, 64, 0, stream>>>(u_raw, v_raw, u_eff, v_eff, beta_u, beta_v);
    hh_kernel<<<(2 * HH) / 4, 256, 0, stream>>>(u_eff, v_eff, beta_u, beta_v, Ucol, Vrow);
    w_kernel<<<HH, HH, 0, stream>>>(Ucol, Vrow, sig, Wm);
    gemm_mfma<float, __half>
        <<<dim3((BB * TT) / 128, HH / 64), 256, 0, stream>>>(x, W_in, b_in, xpbuf, BB * TT, HH, II);
    recur_kernel<<<BB, 512, 0, stream>>>(Wm, xpbuf, hall);
    gemm_mfma<__half, float>
        <<<dim3((BB * TT) / 128, OO / 64), 256, 0, stream>>>(hall, W_out, b_out, out, BB * TT, OO, HH);
}